// Round 14
// baseline (406.744 us; speedup 1.0000x reference)
//
#include <hip/hip_runtime.h>
#include <math.h>

#define NCH 128
#define TE 64    // fallback edge tile
#define TF 64    // fast-path edge tile (37.9 KB LDS -> 4 blocks/CU)
#define AP 296   // msg_in row pad (f16): 592B rows, 16B-aligned for b64/b128
#define AF 132   // f32 message row pad for reduction tail (64x132x4 = 33792 B <= As)
#define XP 136   // node-tile row pad (f16)

typedef __attribute__((ext_vector_type(8))) _Float16 half8;
typedef __attribute__((ext_vector_type(4))) _Float16 half4;
typedef __attribute__((ext_vector_type(4))) float f32x4;

__device__ __forceinline__ float gelu_exact(float v) {
    return 0.5f * v * (1.0f + erff(v * 0.70710678118654752f));
}

// fast erf: Abramowitz-Stegun 7.1.26, |err| <= 1.5e-7
__device__ __forceinline__ float erf_fast(float x) {
    float ax = fabsf(x);
    float t  = __builtin_amdgcn_rcpf(fmaf(0.3275911f, ax, 1.0f));
    float p  = fmaf(t, 1.061405429f, -1.453152027f);
    p = fmaf(t, p, 1.421413741f);
    p = fmaf(t, p, -0.284496736f);
    p = fmaf(t, p, 0.254829592f);
    float e  = exp2f(-ax * ax * 1.4426950408889634f);
    float r  = fmaf(-p * t, e, 1.0f);
    return copysignf(r, x);
}

__device__ __forceinline__ float gelu_fast(float v) {
    return 0.5f * v * (1.0f + erf_fast(v * 0.70710678118654752f));
}

__device__ __forceinline__ half4 cvt4(float4 v) {
#if __has_builtin(__builtin_amdgcn_cvt_pkrtz)
    auto a = __builtin_amdgcn_cvt_pkrtz(v.x, v.y);
    auto b = __builtin_amdgcn_cvt_pkrtz(v.z, v.w);
    half4 r;
    r[0] = a[0]; r[1] = a[1]; r[2] = b[0]; r[3] = b[1];
    return r;
#else
    return (half4){(_Float16)v.x, (_Float16)v.y, (_Float16)v.z, (_Float16)v.w};
#endif
}

// sin/cos of (rev * 2*pi) via HW v_sin/v_cos (input in revolutions, fract-reduced)
__device__ __forceinline__ void sincos_rev(float rev, float* s, float* c) {
    float fr = rev - floorf(rev);
#if __has_builtin(__builtin_amdgcn_sinf) && __has_builtin(__builtin_amdgcn_cosf)
    *s = __builtin_amdgcn_sinf(fr);
    *c = __builtin_amdgcn_cosf(fr);
#else
    float rad = fr * 6.283185307179586f;
    *s = sinf(rad);
    *c = cosf(rad);
#endif
}

// ============ CSR permutation prep ==========================================
__global__ __launch_bounds__(256) void k_hist(const int* __restrict__ ei,
                                              int* __restrict__ cnt, int E) {
    int e = blockIdx.x * 256 + threadIdx.x;
    if (e < E) atomicAdd(&cnt[ei[E + e]], 1);
}

__global__ __launch_bounds__(256) void k_scan_local(const int* __restrict__ cnt,
                                                    int* __restrict__ fill,
                                                    int* __restrict__ bsum, int n) {
    __shared__ int sdata[256];
    const int tid = threadIdx.x;
    const int i = blockIdx.x * 256 + tid;
    int v = (i < n) ? cnt[i] : 0;
    sdata[tid] = v;
    __syncthreads();
    #pragma unroll
    for (int off = 1; off < 256; off <<= 1) {
        int t = (tid >= off) ? sdata[tid - off] : 0;
        __syncthreads();
        sdata[tid] += t;
        __syncthreads();
    }
    if (i < n) fill[i] = sdata[tid] - v;
    if (tid == 255) bsum[blockIdx.x] = sdata[255];
}

__global__ __launch_bounds__(256) void k_scan_bsum(int* __restrict__ bsum, int nb) {
    __shared__ int sdata[256];
    const int tid = threadIdx.x;
    int v = (tid < nb) ? bsum[tid] : 0;
    sdata[tid] = v;
    __syncthreads();
    #pragma unroll
    for (int off = 1; off < 256; off <<= 1) {
        int t = (tid >= off) ? sdata[tid - off] : 0;
        __syncthreads();
        sdata[tid] += t;
        __syncthreads();
    }
    if (tid < nb) bsum[tid] = sdata[tid] - v;
}

__global__ __launch_bounds__(256) void k_scan_serial(const int* __restrict__ cnt,
                                                     int* __restrict__ fill, int n) {
    __shared__ int sdata[256];
    __shared__ int carry;
    const int tid = threadIdx.x;
    if (tid == 0) carry = 0;
    __syncthreads();
    for (int base = 0; base < n; base += 256) {
        int i = base + tid;
        int v = (i < n) ? cnt[i] : 0;
        sdata[tid] = v;
        __syncthreads();
        #pragma unroll
        for (int off = 1; off < 256; off <<= 1) {
            int t = (tid >= off) ? sdata[tid - off] : 0;
            __syncthreads();
            sdata[tid] += t;
            __syncthreads();
        }
        int incl = sdata[tid];
        if (i < n) fill[i] = incl - v + carry;
        __syncthreads();
        if (tid == 255) carry += incl;
        __syncthreads();
    }
}

// permute with fused block-offset add: slot = bsum[d>>8] + fill_local[d]++
__global__ __launch_bounds__(256) void k_permute_off(const int* __restrict__ ei,
                                                     int* __restrict__ fill,
                                                     const int* __restrict__ bsum,
                                                     int* __restrict__ perm, int E) {
    int e = blockIdx.x * 256 + threadIdx.x;
    if (e < E) {
        int d = ei[E + e];
        int slot = bsum[d >> 8] + atomicAdd(&fill[d], 1);
        perm[slot] = e;
    }
}

__global__ __launch_bounds__(256) void k_permute(const int* __restrict__ ei,
                                                 int* __restrict__ fill,
                                                 int* __restrict__ perm, int E) {
    int e = blockIdx.x * 256 + threadIdx.x;
    if (e < E) {
        int d = ei[E + e];
        int slot = atomicAdd(&fill[d], 1);
        perm[slot] = e;
    }
}

// ============ fused weight prep: all 6 weights -> per-lane MFMA fragment order
// NOTE: A-fragment of W^T == B-fragment of W, so this layout serves both the
// old (msg x W) and new (W x msg) operand orders unchanged.
__global__ __launch_bounds__(256) void k_prep_all(
    const float* __restrict__ mw1, const float* __restrict__ mw2,
    const float* __restrict__ mw3, const float* __restrict__ w1,
    const float* __restrict__ w2, const float* __restrict__ w3,
    _Float16* __restrict__ wf, _Float16* __restrict__ awf,
    _Float16* __restrict__ o2f, _Float16* __restrict__ o3f)
{
    int b = blockIdx.x;
    const float* W; _Float16* out; int nch;
    if      (b < 18) { W = mw1; out = wf;             nch = 9; }
    else if (b < 26) { W = mw2; out = wf + 9 * 4096;  nch = 4; b -= 18; }
    else if (b < 34) { W = mw3; out = wf + 13 * 4096; nch = 4; b -= 26; }
    else if (b < 42) { W = w1;  out = awf;            nch = 4; b -= 34; }
    else if (b < 50) { W = w2;  out = o2f;            nch = 4; b -= 42; }
    else             { W = w3;  out = o3f;            nch = 4; b -= 50; }
    int idx = b * 256 + threadIdx.x;
    if (idx >= nch * 512) return;
    int c    = idx >> 9;
    int r    = idx & 511;
    int wv   = r >> 7;
    int nf   = (r >> 6) & 1;
    int lane = r & 63;
    int n  = wv * 32 + nf * 16 + (lane & 15);
    int k0 = c * 32 + (lane >> 4) * 8;
    half8 v;
    #pragma unroll
    for (int j = 0; j < 8; ++j) v[j] = (_Float16)W[(size_t)(k0 + j) * NCH + n];
    *(half8*)(out + (size_t)idx * 8) = v;
}

// ============ Kernel 1 (fast): h = x@w1+b1, streaming B (1 barrier)
__global__ __launch_bounds__(256, 4) void k_aw1_mfma(
    const float* __restrict__ x, const _Float16* __restrict__ awf,
    const float* __restrict__ b1, float* __restrict__ h,
    _Float16* __restrict__ h2, int N)
{
    __shared__ __align__(16) _Float16 Xs[64][XP];

    const int tid  = threadIdx.x;
    const int row0 = blockIdx.x * 64;
    const int lane = tid & 63;
    const int w    = tid >> 6;
    const int lrow = lane & 15;
    const int lk8  = lane >> 4;
    const int n0   = w * 32;

    const half8* bp = (const half8*)awf + (w * 128 + lane);
    half8 b[2][2];
    b[0][0] = bp[0];   b[0][1] = bp[64];
    b[1][0] = bp[512]; b[1][1] = bp[512 + 64];

    #pragma unroll
    for (int t = 0; t < 8; ++t) {
        int idx = tid + t * 256;
        int r = idx >> 5, f4 = idx & 31;
        int gr = row0 + r;
        float4 v = {0.f, 0.f, 0.f, 0.f};
        if (gr < N) v = *(const float4*)(x + (size_t)gr * NCH + f4 * 4);
        *(half4*)&Xs[r][f4 * 4] = cvt4(v);
    }
    __syncthreads();

    f32x4 acc[4][2];
    #pragma unroll
    for (int mb = 0; mb < 4; ++mb)
        #pragma unroll
        for (int nf = 0; nf < 2; ++nf) acc[mb][nf] = (f32x4){0.f, 0.f, 0.f, 0.f};

    #pragma unroll
    for (int i = 0; i < 4; ++i) {
        const int s = i & 1;
        half8 av[4];
        #pragma unroll
        for (int mb = 0; mb < 4; ++mb)
            av[mb] = *(const half8*)&Xs[mb * 16 + lrow][i * 32 + lk8 * 8];
        #pragma unroll
        for (int mb = 0; mb < 4; ++mb) {
            acc[mb][0] = __builtin_amdgcn_mfma_f32_16x16x32_f16(av[mb], b[s][0], acc[mb][0], 0, 0, 0);
            acc[mb][1] = __builtin_amdgcn_mfma_f32_16x16x32_f16(av[mb], b[s][1], acc[mb][1], 0, 0, 0);
        }
        if (i + 2 < 4) {
            b[s][0] = bp[(size_t)(i + 2) * 512];
            b[s][1] = bp[(size_t)(i + 2) * 512 + 64];
        }
    }

    float bi0 = b1[n0 + lrow], bi1 = b1[n0 + 16 + lrow];
    #pragma unroll
    for (int mb = 0; mb < 4; ++mb)
        #pragma unroll
        for (int q = 0; q < 4; ++q) {
            int gr = row0 + mb * 16 + lk8 * 4 + q;
            if (gr < N) {
                float v0 = acc[mb][0][q] + bi0;
                float v1 = acc[mb][1][q] + bi1;
                h[(size_t)gr * NCH + n0 + lrow]       = v0;
                h[(size_t)gr * NCH + n0 + 16 + lrow]  = v1;
                h2[(size_t)gr * NCH + n0 + lrow]      = (_Float16)v0;
                h2[(size_t)gr * NCH + n0 + 16 + lrow] = (_Float16)v1;
            }
        }
}

// ============ Kernel 2 (fast): edge MLP, TF=64, OPERAND-SWAPPED MFMA
// D = W_frag(A) x msg_frag(B): lane's C-frag = 4 consecutive out-channels
// (rows) x 1 edge (col) -> packed b64 epi writes, b128 stash writes.
__global__ __launch_bounds__(256, 4) void k_edges_mfma(
    const int* __restrict__ ei, const float* __restrict__ eattr,
    const float* __restrict__ xpos, const _Float16* __restrict__ h2,
    float* h,                          // f32 atomic target (aliases d_out)
    const int* __restrict__ perm,      // dst-sorted edge permutation
    const _Float16* __restrict__ wf,   // fragment-packed mw1|mw2|mw3 (17 chunks)
    const float* __restrict__ mb1, const float* __restrict__ mb2,
    const float* __restrict__ mb3, int E)
{
    __shared__ __align__(16) _Float16 As[TF][AP];   // 37888 B; reused as f32[64][AF]
    __shared__ int permS[TF], dstS[TF];

    const int tid  = threadIdx.x;
    const int e0   = blockIdx.x * TF;
    const int lane = tid & 63;
    const int w    = tid >> 6;
    const int lrow = lane & 15;
    const int lk8  = lane >> 4;
    const int n0   = w * 32;       // wave's 32 out-channels (M side now)

    // weight A-fragments: same wf layout (A-frag of W^T == B-frag of W)
    const half8* bp = (const half8*)wf + (w * 128 + lane);
    half8 b[2][2];                 // [slot][mf]
    b[0][0] = bp[0];   b[0][1] = bp[64];
    b[1][0] = bp[512]; b[1][1] = bp[512 + 64];

    if (tid < TF) {
        int ge = e0 + tid;
        int pe = (ge < E) ? perm[ge] : -1;
        permS[tid] = pe;
        dstS[tid]  = (pe >= 0) ? ei[E + pe] : -1;
    }
    __syncthreads();

    // ---- stage: issue gathered edge loads, compute trig under them
    float4 ea[8];
    #pragma unroll
    for (int t = 0; t < 8; ++t) {
        int idx = tid + t * 256;
        int pe = permS[idx >> 5];
        ea[t] = (pe >= 0) ? *(const float4*)(eattr + (size_t)pe * NCH + (idx & 31) * 4)
                          : (float4){0.f, 0.f, 0.f, 0.f};
    }
    uint4 hv[4];
    #pragma unroll
    for (int t = 0; t < 4; ++t) {
        int idx = tid + t * 256;
        int pe = permS[idx >> 4];
        int s = (pe >= 0) ? ei[pe] : 0;
        hv[t] = *(const uint4*)(h2 + (size_t)s * NCH + (idx & 15) * 8);
    }

    // trig: 4 threads per edge, 4 (sin,cos) pairs each — HW v_sin/v_cos
    {
        int le = tid >> 2, i0 = tid & 3;
        int pe = permS[le];
        float r = 0.f;
        if (pe >= 0) {
            int s = ei[pe], d = dstS[le];
            float dx = xpos[d * 3 + 0] - xpos[s * 3 + 0];
            float dy = xpos[d * 3 + 1] - xpos[s * 3 + 1];
            float dz = xpos[d * 3 + 2] - xpos[s * 3 + 2];
            r = sqrtf(dx * dx + dy * dy + dz * dz);
        }
        #pragma unroll
        for (int u = 0; u < 4; ++u) {
            int i = i0 + u * 4;
            float omr = 1.5915494309f * exp2f(7.0f - 0.875f * (float)i);
            float sv, cv;
            sincos_rev(r * omr, &sv, &cv);
            As[le][i]      = (_Float16)sv;
            As[le][16 + i] = (_Float16)cv;
        }
    }
    // write-late: convert eattr, copy h2
    #pragma unroll
    for (int t = 0; t < 8; ++t) {
        int idx = tid + t * 256;
        *(half4*)&As[idx >> 5][32 + (idx & 31) * 4] = cvt4(ea[t]);
    }
    #pragma unroll
    for (int t = 0; t < 4; ++t) {
        int idx = tid + t * 256;
        *(uint4*)&As[idx >> 4][160 + (idx & 15) * 8] = hv[t];
    }
    __syncthreads();

    f32x4 acc[2][4];   // [mf out-ch block][nf edge block]
    #pragma unroll
    for (int mf = 0; mf < 2; ++mf)
        #pragma unroll
        for (int nf = 0; nf < 4; ++nf) acc[mf][nf] = (f32x4){0.f, 0.f, 0.f, 0.f};

    // epi: gelu(acc + bias) -> As[edge][channel]; lane writes 4 consecutive
    // channels of one edge = one packed b64 store.
    auto epi = [&](const float* __restrict__ mbv) {
        #pragma unroll
        for (int mf = 0; mf < 2; ++mf) {
            int ch = n0 + mf * 16 + lk8 * 4;
            float4 bb = *(const float4*)(mbv + ch);
            #pragma unroll
            for (int nf = 0; nf < 4; ++nf) {
                int e = nf * 16 + lrow;
                float4 g;
                g.x = gelu_fast(acc[mf][nf][0] + bb.x);
                g.y = gelu_fast(acc[mf][nf][1] + bb.y);
                g.z = gelu_fast(acc[mf][nf][2] + bb.z);
                g.w = gelu_fast(acc[mf][nf][3] + bb.w);
                *(half4*)&As[e][ch] = cvt4(g);
                acc[mf][nf] = (f32x4){0.f, 0.f, 0.f, 0.f};
            }
        }
    };

    // ---- flat 17-chunk pipeline (9 layer1 | 4 layer2 | 4 layer3),
    //      2-slot rolling register prefetch of weight A-frags
    #pragma unroll
    for (int i = 0; i < 17; ++i) {
        const int s  = i & 1;
        const int lc = (i < 9) ? i : (i < 13) ? (i - 9) : (i - 13);
        half8 mv[4];   // msg B-frags: 4 edge blocks
        #pragma unroll
        for (int nf = 0; nf < 4; ++nf)
            mv[nf] = *(const half8*)&As[nf * 16 + lrow][lc * 32 + lk8 * 8];
        __builtin_amdgcn_s_setprio(1);
        #pragma unroll
        for (int nf = 0; nf < 4; ++nf) {
            acc[0][nf] = __builtin_amdgcn_mfma_f32_16x16x32_f16(b[s][0], mv[nf], acc[0][nf], 0, 0, 0);
            acc[1][nf] = __builtin_amdgcn_mfma_f32_16x16x32_f16(b[s][1], mv[nf], acc[1][nf], 0, 0, 0);
        }
        __builtin_amdgcn_s_setprio(0);
        if (i + 2 < 17) {
            b[s][0] = bp[(size_t)(i + 2) * 512];
            b[s][1] = bp[(size_t)(i + 2) * 512 + 64];
        }
        if (i == 8)  { __syncthreads(); epi(mb1); __syncthreads(); }
        if (i == 12) { __syncthreads(); epi(mb2); __syncthreads(); }
    }

    // ---- tail: stash f32 messages (b128 per frag) then sorted-run reduction
    {
        __syncthreads();                      // all layer-3 B-reads done
        float* Asf = (float*)&As[0][0];       // [64][AF]
        #pragma unroll
        for (int mf = 0; mf < 2; ++mf) {
            int ch = n0 + mf * 16 + lk8 * 4;
            float4 bb = *(const float4*)(mb3 + ch);
            #pragma unroll
            for (int nf = 0; nf < 4; ++nf) {
                int e = nf * 16 + lrow;
                float4 vv;
                vv.x = acc[mf][nf][0] + bb.x;
                vv.y = acc[mf][nf][1] + bb.y;
                vv.z = acc[mf][nf][2] + bb.z;
                vv.w = acc[mf][nf][3] + bb.w;
                *(float4*)&Asf[e * AF + ch] = vv;
            }
        }
        __syncthreads();                      // messages visible

        // one channel x 32 sorted edges per thread; dst runs are wave-uniform
        const int c     = tid & 127;
        const int ebase = (tid >> 7) * 32;
        float run = 0.f;
        int prev = -1;
        #pragma unroll
        for (int le = 0; le < 32; ++le) {
            int d = __builtin_amdgcn_readfirstlane(dstS[ebase + le]);
            float v = Asf[(ebase + le) * AF + c];
            if (d != prev) {
                if (prev >= 0) atomicAdd(h + (size_t)prev * NCH + c, run);
                run = 0.f;
                prev = d;
            }
            if (d >= 0) run += v;
        }
        if (prev >= 0) atomicAdd(h + (size_t)prev * NCH + c, run);
    }
}

// ============ Kernel 3 (fast): out = relu(h@w2+b2)@w3+b3, streaming B (3 barriers)
__global__ __launch_bounds__(256, 4) void k_out_mfma(
    const float* h, const _Float16* __restrict__ o2f,
    const float* __restrict__ b2, const _Float16* __restrict__ o3f,
    const float* __restrict__ b3, float* out, int N)
{
    __shared__ __align__(16) _Float16 Xs[64][XP];

    const int tid  = threadIdx.x;
    const int row0 = blockIdx.x * 64;
    const int lane = tid & 63;
    const int w    = tid >> 6;
    const int lrow = lane & 15;
    const int lk8  = lane >> 4;
    const int n0   = w * 32;

    const half8* bp2 = (const half8*)o2f + (w * 128 + lane);
    const half8* bp3 = (const half8*)o3f + (w * 128 + lane);
    half8 b[2][2];
    b[0][0] = bp2[0];   b[0][1] = bp2[64];
    b[1][0] = bp2[512]; b[1][1] = bp2[512 + 64];

    #pragma unroll
    for (int t = 0; t < 8; ++t) {
        int idx = tid + t * 256;
        int r = idx >> 5, f4 = idx & 31;
        int gr = row0 + r;
        float4 v = {0.f, 0.f, 0.f, 0.f};
        if (gr < N) v = *(const float4*)(h + (size_t)gr * NCH + f4 * 4);
        *(half4*)&Xs[r][f4 * 4] = cvt4(v);
    }
    __syncthreads();

    f32x4 acc[4][2];
    #pragma unroll
    for (int mb = 0; mb < 4; ++mb)
        #pragma unroll
        for (int nf = 0; nf < 2; ++nf) acc[mb][nf] = (f32x4){0.f, 0.f, 0.f, 0.f};

    // layer 2: 4 chunks; rolling refill crosses into o3f chunks 0,1
    #pragma unroll
    for (int i = 0; i < 4; ++i) {
        const int s = i & 1;
        half8 av[4];
        #pragma unroll
        for (int mb = 0; mb < 4; ++mb)
            av[mb] = *(const half8*)&Xs[mb * 16 + lrow][i * 32 + lk8 * 8];
        #pragma unroll
        for (int mb = 0; mb < 4; ++mb) {
            acc[mb][0] = __builtin_amdgcn_mfma_f32_16x16x32_f16(av[mb], b[s][0], acc[mb][0], 0, 0, 0);
            acc[mb][1] = __builtin_amdgcn_mfma_f32_16x16x32_f16(av[mb], b[s][1], acc[mb][1], 0, 0, 0);
        }
        if (i + 2 < 4) {
            b[s][0] = bp2[(size_t)(i + 2) * 512];
            b[s][1] = bp2[(size_t)(i + 2) * 512 + 64];
        } else {
            b[s][0] = bp3[(size_t)(i - 2) * 512];
            b[s][1] = bp3[(size_t)(i - 2) * 512 + 64];
        }
    }
    __syncthreads();

    {
        float bi0 = b2[n0 + lrow], bi1 = b2[n0 + 16 + lrow];
        #pragma unroll
        for (int mb = 0; mb < 4; ++mb)
            #pragma unroll
            for (int nf = 0; nf < 2; ++nf) {
                float bb = nf ? bi1 : bi0;
                #pragma unroll
                for (int q = 0; q < 4; ++q) {
                    float g = fmaxf(acc[mb][nf][q] + bb, 0.f);
                    Xs[mb * 16 + lk8 * 4 + q][n0 + nf * 16 + lrow] = (_Float16)g;
                }
                acc[mb][nf] = (f32x4){0.f, 0.f, 0.f, 0.f};
            }
    }
    __syncthreads();

    // layer 3: 4 chunks (slots pre-loaded with o3f chunks 0,1)
    #pragma unroll
    for (int i = 0; i < 4; ++i) {
        const int s = i & 1;
        half8 av[4];
        #pragma unroll
        for (int mb = 0; mb < 4; ++mb)
            av[mb] = *(const half8*)&Xs[mb * 16 + lrow][i * 32 + lk8 * 8];
        #pragma unroll
        for (int mb = 0; mb < 4; ++mb) {
            acc[mb][0] = __builtin_amdgcn_mfma_f32_16x16x32_f16(av[mb], b[s][0], acc[mb][0], 0, 0, 0);
            acc[mb][1] = __builtin_amdgcn_mfma_f32_16x16x32_f16(av[mb], b[s][1], acc[mb][1], 0, 0, 0);
        }
        if (i + 2 < 4) {
            b[s][0] = bp3[(size_t)(i + 2) * 512];
            b[s][1] = bp3[(size_t)(i + 2) * 512 + 64];
        }
    }

    float bi0 = b3[n0 + lrow], bi1 = b3[n0 + 16 + lrow];
    #pragma unroll
    for (int mb = 0; mb < 4; ++mb)
        #pragma unroll
        for (int q = 0; q < 4; ++q) {
            int gr = row0 + mb * 16 + lk8 * 4 + q;
            if (gr < N) {
                out[(size_t)gr * NCH + n0 + lrow]      = acc[mb][0][q] + bi0;
                out[(size_t)gr * NCH + n0 + 16 + lrow] = acc[mb][1][q] + bi1;
            }
        }
}

// ==================== fp32 fallback path (round-1, proven) ====================
__global__ __launch_bounds__(256) void k_atomwise1(
    const float* __restrict__ x, const float* __restrict__ w1,
    const float* __restrict__ b1, float* __restrict__ h,
    float* __restrict__ h2, int N)
{
    __shared__ float xs[16][NCH];
    const int row0 = blockIdx.x * 16;
    const int tid = threadIdx.x;
    #pragma unroll
    for (int t = 0; t < 8; ++t) {
        int idx = tid + t * 256;
        int r = idx >> 7, c = idx & 127;
        int gr = row0 + r;
        xs[r][c] = (gr < N) ? x[(size_t)gr * NCH + c] : 0.f;
    }
    __syncthreads();
    const int j = tid & 127;
    const int rg = tid >> 7;
    float acc[8];
    #pragma unroll
    for (int i = 0; i < 8; ++i) acc[i] = 0.f;
    for (int k = 0; k < NCH; ++k) {
        float wv = w1[(size_t)k * NCH + j];
        #pragma unroll
        for (int i = 0; i < 8; ++i)
            acc[i] = fmaf(xs[rg * 8 + i][k], wv, acc[i]);
    }
    float bv = b1[j];
    #pragma unroll
    for (int i = 0; i < 8; ++i) {
        int gr = row0 + rg * 8 + i;
        if (gr < N) {
            float v = acc[i] + bv;
            h[(size_t)gr * NCH + j]  = v;
            h2[(size_t)gr * NCH + j] = v;
        }
    }
}

__global__ __launch_bounds__(256) void k_edges_f32(
    const int* __restrict__ ei, const float* __restrict__ eattr,
    const float* __restrict__ xpos, const float* __restrict__ h,
    const float* __restrict__ mw1, const float* __restrict__ mb1,
    const float* __restrict__ mw2, const float* __restrict__ mb2,
    const float* __restrict__ mw3, const float* __restrict__ mb3,
    float* __restrict__ agg, int E)
{
    __shared__ __align__(16) float Asf[TE][292];
    __shared__ float Wsf[32][NCH];
    __shared__ int srcS[TE];
    __shared__ int dstS[TE];
    const int tid = threadIdx.x;
    const int e0 = blockIdx.x * TE;
    if (tid < TE) {
        int e = e0 + tid;
        int s = 0, d = -1;
        float r = 0.f;
        if (e < E) {
            s = ei[e]; d = ei[E + e];
            float dx = xpos[d * 3 + 0] - xpos[s * 3 + 0];
            float dy = xpos[d * 3 + 1] - xpos[s * 3 + 1];
            float dz = xpos[d * 3 + 2] - xpos[s * 3 + 2];
            r = sqrtf(dx * dx + dy * dy + dz * dz);
        }
        srcS[tid] = s; dstS[tid] = d;
        #pragma unroll
        for (int i = 0; i < 16; ++i) {
            float om = 10.f * exp2f(7.0f - 0.875f * (float)i);
            float f = r * om;
            Asf[tid][i] = sinf(f); Asf[tid][16 + i] = cosf(f);
        }
    }
    __syncthreads();
    {
        const int half = tid >> 7;
        const int c = tid & 127;
        for (int ee = 0; ee < TE; ee += 2) {
            int le = ee + half;
            int e = e0 + le;
            if (e < E) {
                Asf[le][32 + c]  = eattr[(size_t)e * NCH + c];
                Asf[le][160 + c] = h[(size_t)srcS[le] * NCH + c];
            } else { Asf[le][32 + c] = 0.f; Asf[le][160 + c] = 0.f; }
        }
    }
    const int jl = tid & 31;
    const int g  = tid >> 5;
    float acc[8][4];
    auto run_layer = [&](const float* __restrict__ Wg, int K) {
        #pragma unroll
        for (int i = 0; i < 8; ++i)
            #pragma unroll
            for (int c = 0; c < 4; ++c) acc[i][c] = 0.f;
        for (int k0 = 0; k0 < K; k0 += 32) {
            __syncthreads();
            #pragma unroll
            for (int t = 0; t < 16; ++t) {
                int idx = tid + t * 256;
                Wsf[idx >> 7][idx & 127] =
                    Wg[(size_t)(k0 + (idx >> 7)) * NCH + (idx & 127)];
            }
            __syncthreads();
            #pragma unroll
            for (int kk = 0; kk < 32; kk += 4) {
                float4 a[8];
                #pragma unroll
                for (int i = 0; i < 8; ++i)
                    a[i] = *reinterpret_cast<const float4*>(&Asf[g * 8 + i][k0 + kk]);
                #pragma unroll
                for (int u = 0; u < 4; ++u) {
                    float w0 = Wsf[kk + u][jl];
                    float w1v = Wsf[kk + u][jl + 32];
                    float w2v = Wsf[kk + u][jl + 64];
                    float w3v = Wsf[kk + u][jl + 96];
                    #pragma unroll
                    for (int i = 0; i < 8; ++i) {
                        float avv = (&a[i].x)[u];
                        acc[i][0] = fmaf(avv, w0, acc[i][0]);
                        acc[i][1] = fmaf(avv, w1v, acc[i][1]);
                        acc[i][2] = fmaf(avv, w2v, acc[i][2]);
                        acc[i][3] = fmaf(avv, w3v, acc[i][3]);
                    }
                }
            }
        }
    };
    run_layer(mw1, 288);
    #pragma unroll
    for (int i = 0; i < 8; ++i)
        #pragma unroll
        for (int c = 0; c < 4; ++c) {
            int j = jl + 32 * c;
            Asf[g * 8 + i][j] = gelu_exact(acc[i][c] + mb1[j]);
        }
    run_layer(mw2, 128);
    #pragma unroll
    for (int i = 0; i < 8; ++i)
        #pragma unroll
        for (int c = 0; c < 4; ++c) {
            int j = jl + 32 * c;
            Asf[g * 8 + i][j] = gelu_exact(acc[i][c] + mb2[j]);
        }
    run_layer(mw3, 128);
    #pragma unroll
    for (int i = 0; i < 8; ++i) {
        int d = dstS[g * 8 + i];
        if (d >= 0) {
            #pragma unroll
            for (int c = 0; c < 4; ++c) {
                int j = jl + 32 * c;
                atomicAdd(&agg[(size_t)d * NCH + j], acc[i][c] + mb3[j]);
            }
        }
    }
}

__global__ __launch_bounds__(256) void k_out(
    const float* h, const float* aggOpt,
    const float* __restrict__ w2, const float* __restrict__ b2,
    const float* __restrict__ w3, const float* __restrict__ b3,
    float* out, int N)
{
    __shared__ float hs[16][NCH];
    __shared__ float ts[16][NCH];
    const int row0 = blockIdx.x * 16;
    const int tid = threadIdx.x;
    #pragma unroll
    for (int t = 0; t < 8; ++t) {
        int idx = tid + t * 256;
        int r = idx >> 7, c = idx & 127;
        int gr = row0 + r;
        float v = 0.f;
        if (gr < N) {
            v = h[(size_t)gr * NCH + c];
            if (aggOpt) v += aggOpt[(size_t)gr * NCH + c];
        }
        hs[r][c] = v;
    }
    __syncthreads();
    const int j = tid & 127;
    const int rg = tid >> 7;
    float acc[8];
    #pragma unroll
    for (int i = 0; i < 8; ++i) acc[i] = 0.f;
    for (int k = 0; k < NCH; ++k) {
        float wv = w2[(size_t)k * NCH + j];
        #pragma unroll
        for (int i = 0; i < 8; ++i)
            acc[i] = fmaf(hs[rg * 8 + i][k], wv, acc[i]);
    }
    float bv = b2[j];
    #pragma unroll
    for (int i = 0; i < 8; ++i)
        ts[rg * 8 + i][j] = fmaxf(acc[i] + bv, 0.f);
    __syncthreads();
    float acc2[8];
    #pragma unroll
    for (int i = 0; i < 8; ++i) acc2[i] = 0.f;
    for (int k = 0; k < NCH; ++k) {
        float wv = w3[(size_t)k * NCH + j];
        #pragma unroll
        for (int i = 0; i < 8; ++i)
            acc2[i] = fmaf(ts[rg * 8 + i][k], wv, acc2[i]);
    }
    float b3v = b3[j];
    #pragma unroll
    for (int i = 0; i < 8; ++i) {
        int gr = row0 + rg * 8 + i;
        if (gr < N) out[(size_t)gr * NCH + j] = acc2[i] + b3v;
    }
}

extern "C" void kernel_launch(void* const* d_in, const int* in_sizes, int n_in,
                              void* d_out, int out_size, void* d_ws, size_t ws_size,
                              hipStream_t stream)
{
    const float* x     = (const float*)d_in[0];
    const int*   ei    = (const int*)d_in[1];
    const float* eattr = (const float*)d_in[2];
    const float* xpos  = (const float*)d_in[3];
    const float* w1    = (const float*)d_in[4];
    const float* b1    = (const float*)d_in[5];
    const float* mw1   = (const float*)d_in[6];
    const float* mb1   = (const float*)d_in[7];
    const float* mw2   = (const float*)d_in[8];
    const float* mb2   = (const float*)d_in[9];
    const float* mw3   = (const float*)d_in[10];
    const float* mb3   = (const float*)d_in[11];
    const float* w2    = (const float*)d_in[12];
    const float* b2    = (const float*)d_in[13];
    const float* w3    = (const float*)d_in[14];
    const float* b3    = (const float*)d_in[15];

    const int N = in_sizes[0] / NCH;
    const int E = in_sizes[1] / 2;

    float* h = (float*)d_out;

    const int nbscan = (N + 255) / 256;
    const size_t h2_bytes = (size_t)N * NCH * sizeof(_Float16);
    const size_t wchunks  = 17 + 4 + 4 + 4;   // wf | awf | o2f | o3f (frag-packed)
    const size_t wbytes   = wchunks * 4096 * sizeof(_Float16);
    const size_t csr_bytes = ((size_t)2 * N + E + nbscan) * sizeof(int);
    const bool fast = ws_size >= h2_bytes + wbytes + csr_bytes;

    if (fast) {
        _Float16* h2  = (_Float16*)d_ws;
        _Float16* wf  = (_Float16*)((char*)d_ws + h2_bytes);
        _Float16* awf = wf + 17 * 4096;
        _Float16* o2f = awf + 4 * 4096;
        _Float16* o3f = o2f + 4 * 4096;
        int* cnt  = (int*)(o3f + 4 * 4096);
        int* fill = cnt + N;
        int* perm = fill + N;
        int* bsum = perm + E;

        // CSR permutation: hist -> parallel scan -> scatter(+offset)
        hipMemsetAsync(cnt, 0, (size_t)N * sizeof(int), stream);
        k_hist<<<(E + 255) / 256, 256, 0, stream>>>(ei, cnt, E);
        if (nbscan <= 256) {
            k_scan_local<<<nbscan, 256, 0, stream>>>(cnt, fill, bsum, N);
            k_scan_bsum<<<1, 256, 0, stream>>>(bsum, nbscan);
            k_permute_off<<<(E + 255) / 256, 256, 0, stream>>>(ei, fill, bsum, perm, E);
        } else {
            k_scan_serial<<<1, 256, 0, stream>>>(cnt, fill, N);
            k_permute<<<(E + 255) / 256, 256, 0, stream>>>(ei, fill, perm, E);
        }

        k_prep_all<<<58, 256, 0, stream>>>(mw1, mw2, mw3, w1, w2, w3,
                                           wf, awf, o2f, o3f);
        const int nb = (N + 63) / 64;
        k_aw1_mfma<<<nb, 256, 0, stream>>>(x, awf, b1, h, h2, N);
        k_edges_mfma<<<(E + TF - 1) / TF, 256, 0, stream>>>(
            ei, eattr, xpos, h2, h, perm, wf, mb1, mb2, mb3, E);
        k_out_mfma<<<nb, 256, 0, stream>>>(h, o2f, b2, o3f, b3, (float*)d_out, N);
    } else {
        float* agg = (float*)d_ws;
        k_atomwise1<<<(N + 15) / 16, 256, 0, stream>>>(x, w1, b1, h, agg, N);
        hipMemsetAsync(agg, 0, (size_t)N * NCH * sizeof(float), stream);
        k_edges_f32<<<(E + TE - 1) / TE, 256, 0, stream>>>(
            ei, eattr, xpos, h, mw1, mb1, mw2, mb2, mw3, mb3, agg, E);
        k_out<<<(N + 15) / 16, 256, 0, stream>>>(h, agg, w2, b2, w3, b3,
                                                 (float*)d_out, N);
    }
}

// Round 15
// 369.081 us; speedup vs baseline: 1.1020x; 1.1020x over previous
//
#include <hip/hip_runtime.h>
#include <math.h>

#define NCH 128
#define TE 64    // fallback edge tile
#define TF 64    // fast-path edge tile (37.9 KB LDS -> 4 blocks/CU)
#define AP 296   // msg_in row pad (f16): 592B rows, 16B-aligned for b64/b128
#define AF 132   // f32 message row pad for reduction tail (64x132x4 = 33792 B <= As)
#define XP 136   // node-tile row pad (f16)

typedef __attribute__((ext_vector_type(8))) _Float16 half8;
typedef __attribute__((ext_vector_type(4))) _Float16 half4;
typedef __attribute__((ext_vector_type(4))) float f32x4;

__device__ __forceinline__ float gelu_exact(float v) {
    return 0.5f * v * (1.0f + erff(v * 0.70710678118654752f));
}

// tanh-form GELU: x - x/(exp(2z)+1), 2z = 1.59576912*(x + 0.044715 x^3)
// max |err| vs erf-GELU ~3e-4; 6 VALU + 2 trans (was 10 + 2). Saturates
// correctly: exp2->inf => rcp->0 => x; exp2->0 => r=1 => 0.
__device__ __forceinline__ float gelu_fast(float v) {
    float x2  = v * v;
    float t   = fmaf(0.044715f, x2, 1.0f);
    float arg = (v * 2.3022165f) * t;      // 1.59576912 * log2(e) folded
    float e   = exp2f(arg);
    float r   = __builtin_amdgcn_rcpf(e + 1.0f);
    return fmaf(-v, r, v);
}

__device__ __forceinline__ half4 cvt4(float4 v) {
#if __has_builtin(__builtin_amdgcn_cvt_pkrtz)
    auto a = __builtin_amdgcn_cvt_pkrtz(v.x, v.y);
    auto b = __builtin_amdgcn_cvt_pkrtz(v.z, v.w);
    half4 r;
    r[0] = a[0]; r[1] = a[1]; r[2] = b[0]; r[3] = b[1];
    return r;
#else
    return (half4){(_Float16)v.x, (_Float16)v.y, (_Float16)v.z, (_Float16)v.w};
#endif
}

// sin/cos of (rev * 2*pi) via HW v_sin/v_cos (input in revolutions, fract-reduced)
__device__ __forceinline__ void sincos_rev(float rev, float* s, float* c) {
    float fr = rev - floorf(rev);
#if __has_builtin(__builtin_amdgcn_sinf) && __has_builtin(__builtin_amdgcn_cosf)
    *s = __builtin_amdgcn_sinf(fr);
    *c = __builtin_amdgcn_cosf(fr);
#else
    float rad = fr * 6.283185307179586f;
    *s = sinf(rad);
    *c = cosf(rad);
#endif
}

// ============ fused hist + weight prep (independent work, one launch) ========
// blocks [0, nh): dst histogram; [nh, nh+58): frag-pack all 6 weights.
__global__ __launch_bounds__(256) void k_hist_prep(
    const int* __restrict__ ei, int* __restrict__ cnt, int E, int nh,
    const float* __restrict__ mw1, const float* __restrict__ mw2,
    const float* __restrict__ mw3, const float* __restrict__ w1,
    const float* __restrict__ w2, const float* __restrict__ w3,
    _Float16* __restrict__ wf, _Float16* __restrict__ awf,
    _Float16* __restrict__ o2f, _Float16* __restrict__ o3f)
{
    int bb = blockIdx.x;
    if (bb < nh) {
        int e = bb * 256 + threadIdx.x;
        if (e < E) atomicAdd(&cnt[ei[E + e]], 1);
        return;
    }
    int b = bb - nh;
    const float* W; _Float16* out; int nch;
    if      (b < 18) { W = mw1; out = wf;             nch = 9; }
    else if (b < 26) { W = mw2; out = wf + 9 * 4096;  nch = 4; b -= 18; }
    else if (b < 34) { W = mw3; out = wf + 13 * 4096; nch = 4; b -= 26; }
    else if (b < 42) { W = w1;  out = awf;            nch = 4; b -= 34; }
    else if (b < 50) { W = w2;  out = o2f;            nch = 4; b -= 42; }
    else             { W = w3;  out = o3f;            nch = 4; b -= 50; }
    int idx = b * 256 + threadIdx.x;
    if (idx >= nch * 512) return;
    int c    = idx >> 9;
    int r    = idx & 511;
    int wv   = r >> 7;
    int nf   = (r >> 6) & 1;
    int lane = r & 63;
    int n  = wv * 32 + nf * 16 + (lane & 15);
    int k0 = c * 32 + (lane >> 4) * 8;
    half8 v;
    #pragma unroll
    for (int j = 0; j < 8; ++j) v[j] = (_Float16)W[(size_t)(k0 + j) * NCH + n];
    *(half8*)(out + (size_t)idx * 8) = v;
}

// ============ CSR scan ======================================================
__global__ __launch_bounds__(256) void k_scan_local(const int* __restrict__ cnt,
                                                    int* __restrict__ fill,
                                                    int* __restrict__ bsum, int n) {
    __shared__ int sdata[256];
    const int tid = threadIdx.x;
    const int i = blockIdx.x * 256 + tid;
    int v = (i < n) ? cnt[i] : 0;
    sdata[tid] = v;
    __syncthreads();
    #pragma unroll
    for (int off = 1; off < 256; off <<= 1) {
        int t = (tid >= off) ? sdata[tid - off] : 0;
        __syncthreads();
        sdata[tid] += t;
        __syncthreads();
    }
    if (i < n) fill[i] = sdata[tid] - v;
    if (tid == 255) bsum[blockIdx.x] = sdata[255];
}

__global__ __launch_bounds__(256) void k_scan_bsum(int* __restrict__ bsum, int nb) {
    __shared__ int sdata[256];
    const int tid = threadIdx.x;
    int v = (tid < nb) ? bsum[tid] : 0;
    sdata[tid] = v;
    __syncthreads();
    #pragma unroll
    for (int off = 1; off < 256; off <<= 1) {
        int t = (tid >= off) ? sdata[tid - off] : 0;
        __syncthreads();
        sdata[tid] += t;
        __syncthreads();
    }
    if (tid < nb) bsum[tid] = sdata[tid] - v;
}

__global__ __launch_bounds__(256) void k_scan_serial(const int* __restrict__ cnt,
                                                     int* __restrict__ fill, int n) {
    __shared__ int sdata[256];
    __shared__ int carry;
    const int tid = threadIdx.x;
    if (tid == 0) carry = 0;
    __syncthreads();
    for (int base = 0; base < n; base += 256) {
        int i = base + tid;
        int v = (i < n) ? cnt[i] : 0;
        sdata[tid] = v;
        __syncthreads();
        #pragma unroll
        for (int off = 1; off < 256; off <<= 1) {
            int t = (tid >= off) ? sdata[tid - off] : 0;
            __syncthreads();
            sdata[tid] += t;
            __syncthreads();
        }
        int incl = sdata[tid];
        if (i < n) fill[i] = incl - v + carry;
        __syncthreads();
        if (tid == 255) carry += incl;
        __syncthreads();
    }
}

// permute with fused block-offset add: slot = bsum[d>>8] + fill_local[d]++
__global__ __launch_bounds__(256) void k_permute_off(const int* __restrict__ ei,
                                                     int* __restrict__ fill,
                                                     const int* __restrict__ bsum,
                                                     int* __restrict__ perm, int E) {
    int e = blockIdx.x * 256 + threadIdx.x;
    if (e < E) {
        int d = ei[E + e];
        int slot = bsum[d >> 8] + atomicAdd(&fill[d], 1);
        perm[slot] = e;
    }
}

__global__ __launch_bounds__(256) void k_permute(const int* __restrict__ ei,
                                                 int* __restrict__ fill,
                                                 int* __restrict__ perm, int E) {
    int e = blockIdx.x * 256 + threadIdx.x;
    if (e < E) {
        int d = ei[E + e];
        int slot = atomicAdd(&fill[d], 1);
        perm[slot] = e;
    }
}

// ============ Kernel 1 (fast): h = x@w1+b1, streaming B (1 barrier)
__global__ __launch_bounds__(256, 4) void k_aw1_mfma(
    const float* __restrict__ x, const _Float16* __restrict__ awf,
    const float* __restrict__ b1, float* __restrict__ h,
    _Float16* __restrict__ h2, int N)
{
    __shared__ __align__(16) _Float16 Xs[64][XP];

    const int tid  = threadIdx.x;
    const int row0 = blockIdx.x * 64;
    const int lane = tid & 63;
    const int w    = tid >> 6;
    const int lrow = lane & 15;
    const int lk8  = lane >> 4;
    const int n0   = w * 32;

    const half8* bp = (const half8*)awf + (w * 128 + lane);
    half8 b[2][2];
    b[0][0] = bp[0];   b[0][1] = bp[64];
    b[1][0] = bp[512]; b[1][1] = bp[512 + 64];

    #pragma unroll
    for (int t = 0; t < 8; ++t) {
        int idx = tid + t * 256;
        int r = idx >> 5, f4 = idx & 31;
        int gr = row0 + r;
        float4 v = {0.f, 0.f, 0.f, 0.f};
        if (gr < N) v = *(const float4*)(x + (size_t)gr * NCH + f4 * 4);
        *(half4*)&Xs[r][f4 * 4] = cvt4(v);
    }
    __syncthreads();

    f32x4 acc[4][2];
    #pragma unroll
    for (int mb = 0; mb < 4; ++mb)
        #pragma unroll
        for (int nf = 0; nf < 2; ++nf) acc[mb][nf] = (f32x4){0.f, 0.f, 0.f, 0.f};

    #pragma unroll
    for (int i = 0; i < 4; ++i) {
        const int s = i & 1;
        half8 av[4];
        #pragma unroll
        for (int mb = 0; mb < 4; ++mb)
            av[mb] = *(const half8*)&Xs[mb * 16 + lrow][i * 32 + lk8 * 8];
        #pragma unroll
        for (int mb = 0; mb < 4; ++mb) {
            acc[mb][0] = __builtin_amdgcn_mfma_f32_16x16x32_f16(av[mb], b[s][0], acc[mb][0], 0, 0, 0);
            acc[mb][1] = __builtin_amdgcn_mfma_f32_16x16x32_f16(av[mb], b[s][1], acc[mb][1], 0, 0, 0);
        }
        if (i + 2 < 4) {
            b[s][0] = bp[(size_t)(i + 2) * 512];
            b[s][1] = bp[(size_t)(i + 2) * 512 + 64];
        }
    }

    float bi0 = b1[n0 + lrow], bi1 = b1[n0 + 16 + lrow];
    #pragma unroll
    for (int mb = 0; mb < 4; ++mb)
        #pragma unroll
        for (int q = 0; q < 4; ++q) {
            int gr = row0 + mb * 16 + lk8 * 4 + q;
            if (gr < N) {
                float v0 = acc[mb][0][q] + bi0;
                float v1 = acc[mb][1][q] + bi1;
                h[(size_t)gr * NCH + n0 + lrow]       = v0;
                h[(size_t)gr * NCH + n0 + 16 + lrow]  = v1;
                h2[(size_t)gr * NCH + n0 + lrow]      = (_Float16)v0;
                h2[(size_t)gr * NCH + n0 + 16 + lrow] = (_Float16)v1;
            }
        }
}

// ============ Kernel 2 (fast): edge MLP, TF=64, operand-swapped MFMA
__global__ __launch_bounds__(256, 4) void k_edges_mfma(
    const int* __restrict__ ei, const float* __restrict__ eattr,
    const float* __restrict__ xpos, const _Float16* __restrict__ h2,
    float* h,                          // f32 atomic target (aliases d_out)
    const int* __restrict__ perm,      // dst-sorted edge permutation
    const _Float16* __restrict__ wf,   // fragment-packed mw1|mw2|mw3 (17 chunks)
    const float* __restrict__ mb1, const float* __restrict__ mb2,
    const float* __restrict__ mb3, int E)
{
    __shared__ __align__(16) _Float16 As[TF][AP];   // 37888 B; reused as f32[64][AF]
    __shared__ int permS[TF], dstS[TF];

    const int tid  = threadIdx.x;
    const int e0   = blockIdx.x * TF;
    const int lane = tid & 63;
    const int w    = tid >> 6;
    const int lrow = lane & 15;
    const int lk8  = lane >> 4;
    const int n0   = w * 32;       // wave's 32 out-channels (M side)

    const half8* bp = (const half8*)wf + (w * 128 + lane);
    half8 b[2][2];
    b[0][0] = bp[0];   b[0][1] = bp[64];
    b[1][0] = bp[512]; b[1][1] = bp[512 + 64];

    if (tid < TF) {
        int ge = e0 + tid;
        int pe = (ge < E) ? perm[ge] : -1;
        permS[tid] = pe;
        dstS[tid]  = (pe >= 0) ? ei[E + pe] : -1;
    }
    __syncthreads();

    // ---- stage: issue gathered edge loads, compute trig under them
    float4 ea[8];
    #pragma unroll
    for (int t = 0; t < 8; ++t) {
        int idx = tid + t * 256;
        int pe = permS[idx >> 5];
        ea[t] = (pe >= 0) ? *(const float4*)(eattr + (size_t)pe * NCH + (idx & 31) * 4)
                          : (float4){0.f, 0.f, 0.f, 0.f};
    }
    uint4 hv[4];
    #pragma unroll
    for (int t = 0; t < 4; ++t) {
        int idx = tid + t * 256;
        int pe = permS[idx >> 4];
        int s = (pe >= 0) ? ei[pe] : 0;
        hv[t] = *(const uint4*)(h2 + (size_t)s * NCH + (idx & 15) * 8);
    }

    // trig: 4 threads per edge, 4 (sin,cos) pairs each — HW v_sin/v_cos
    {
        int le = tid >> 2, i0 = tid & 3;
        int pe = permS[le];
        float r = 0.f;
        if (pe >= 0) {
            int s = ei[pe], d = dstS[le];
            float dx = xpos[d * 3 + 0] - xpos[s * 3 + 0];
            float dy = xpos[d * 3 + 1] - xpos[s * 3 + 1];
            float dz = xpos[d * 3 + 2] - xpos[s * 3 + 2];
            r = sqrtf(dx * dx + dy * dy + dz * dz);
        }
        #pragma unroll
        for (int u = 0; u < 4; ++u) {
            int i = i0 + u * 4;
            float omr = 1.5915494309f * exp2f(7.0f - 0.875f * (float)i);
            float sv, cv;
            sincos_rev(r * omr, &sv, &cv);
            As[le][i]      = (_Float16)sv;
            As[le][16 + i] = (_Float16)cv;
        }
    }
    // write-late: convert eattr, copy h2
    #pragma unroll
    for (int t = 0; t < 8; ++t) {
        int idx = tid + t * 256;
        *(half4*)&As[idx >> 5][32 + (idx & 31) * 4] = cvt4(ea[t]);
    }
    #pragma unroll
    for (int t = 0; t < 4; ++t) {
        int idx = tid + t * 256;
        *(uint4*)&As[idx >> 4][160 + (idx & 15) * 8] = hv[t];
    }
    __syncthreads();

    f32x4 acc[2][4];   // [mf out-ch block][nf edge block]
    #pragma unroll
    for (int mf = 0; mf < 2; ++mf)
        #pragma unroll
        for (int nf = 0; nf < 4; ++nf) acc[mf][nf] = (f32x4){0.f, 0.f, 0.f, 0.f};

    // epi: gelu(acc + bias) -> As[edge][channel]; lane writes 4 consecutive
    // channels of one edge = one packed b64 store.
    auto epi = [&](const float* __restrict__ mbv) {
        #pragma unroll
        for (int mf = 0; mf < 2; ++mf) {
            int ch = n0 + mf * 16 + lk8 * 4;
            float4 bb = *(const float4*)(mbv + ch);
            #pragma unroll
            for (int nf = 0; nf < 4; ++nf) {
                int e = nf * 16 + lrow;
                float4 g;
                g.x = gelu_fast(acc[mf][nf][0] + bb.x);
                g.y = gelu_fast(acc[mf][nf][1] + bb.y);
                g.z = gelu_fast(acc[mf][nf][2] + bb.z);
                g.w = gelu_fast(acc[mf][nf][3] + bb.w);
                *(half4*)&As[e][ch] = cvt4(g);
                acc[mf][nf] = (f32x4){0.f, 0.f, 0.f, 0.f};
            }
        }
    };

    // ---- flat 17-chunk pipeline (9 layer1 | 4 layer2 | 4 layer3),
    //      2-slot rolling register prefetch of weight A-frags
    #pragma unroll
    for (int i = 0; i < 17; ++i) {
        const int s  = i & 1;
        const int lc = (i < 9) ? i : (i < 13) ? (i - 9) : (i - 13);
        half8 mv[4];   // msg B-frags: 4 edge blocks
        #pragma unroll
        for (int nf = 0; nf < 4; ++nf)
            mv[nf] = *(const half8*)&As[nf * 16 + lrow][lc * 32 + lk8 * 8];
        __builtin_amdgcn_s_setprio(1);
        #pragma unroll
        for (int nf = 0; nf < 4; ++nf) {
            acc[0][nf] = __builtin_amdgcn_mfma_f32_16x16x32_f16(b[s][0], mv[nf], acc[0][nf], 0, 0, 0);
            acc[1][nf] = __builtin_amdgcn_mfma_f32_16x16x32_f16(b[s][1], mv[nf], acc[1][nf], 0, 0, 0);
        }
        __builtin_amdgcn_s_setprio(0);
        if (i + 2 < 17) {
            b[s][0] = bp[(size_t)(i + 2) * 512];
            b[s][1] = bp[(size_t)(i + 2) * 512 + 64];
        }
        if (i == 8)  { __syncthreads(); epi(mb1); __syncthreads(); }
        if (i == 12) { __syncthreads(); epi(mb2); __syncthreads(); }
    }

    // ---- tail: stash f32 messages (b128 per frag) then sorted-run reduction
    {
        __syncthreads();                      // all layer-3 B-reads done
        float* Asf = (float*)&As[0][0];       // [64][AF]
        #pragma unroll
        for (int mf = 0; mf < 2; ++mf) {
            int ch = n0 + mf * 16 + lk8 * 4;
            float4 bb = *(const float4*)(mb3 + ch);
            #pragma unroll
            for (int nf = 0; nf < 4; ++nf) {
                int e = nf * 16 + lrow;
                float4 vv;
                vv.x = acc[mf][nf][0] + bb.x;
                vv.y = acc[mf][nf][1] + bb.y;
                vv.z = acc[mf][nf][2] + bb.z;
                vv.w = acc[mf][nf][3] + bb.w;
                *(float4*)&Asf[e * AF + ch] = vv;
            }
        }
        __syncthreads();                      // messages visible

        // one channel x 32 sorted edges per thread; dst runs are wave-uniform
        const int c     = tid & 127;
        const int ebase = (tid >> 7) * 32;
        float run = 0.f;
        int prev = -1;
        #pragma unroll
        for (int le = 0; le < 32; ++le) {
            int d = __builtin_amdgcn_readfirstlane(dstS[ebase + le]);
            float v = Asf[(ebase + le) * AF + c];
            if (d != prev) {
                if (prev >= 0) atomicAdd(h + (size_t)prev * NCH + c, run);
                run = 0.f;
                prev = d;
            }
            if (d >= 0) run += v;
        }
        if (prev >= 0) atomicAdd(h + (size_t)prev * NCH + c, run);
    }
}

// ============ Kernel 3 (fast): out = relu(h@w2+b2)@w3+b3, streaming B (3 barriers)
__global__ __launch_bounds__(256, 4) void k_out_mfma(
    const float* h, const _Float16* __restrict__ o2f,
    const float* __restrict__ b2, const _Float16* __restrict__ o3f,
    const float* __restrict__ b3, float* out, int N)
{
    __shared__ __align__(16) _Float16 Xs[64][XP];

    const int tid  = threadIdx.x;
    const int row0 = blockIdx.x * 64;
    const int lane = tid & 63;
    const int w    = tid >> 6;
    const int lrow = lane & 15;
    const int lk8  = lane >> 4;
    const int n0   = w * 32;

    const half8* bp2 = (const half8*)o2f + (w * 128 + lane);
    const half8* bp3 = (const half8*)o3f + (w * 128 + lane);
    half8 b[2][2];
    b[0][0] = bp2[0];   b[0][1] = bp2[64];
    b[1][0] = bp2[512]; b[1][1] = bp2[512 + 64];

    #pragma unroll
    for (int t = 0; t < 8; ++t) {
        int idx = tid + t * 256;
        int r = idx >> 5, f4 = idx & 31;
        int gr = row0 + r;
        float4 v = {0.f, 0.f, 0.f, 0.f};
        if (gr < N) v = *(const float4*)(h + (size_t)gr * NCH + f4 * 4);
        *(half4*)&Xs[r][f4 * 4] = cvt4(v);
    }
    __syncthreads();

    f32x4 acc[4][2];
    #pragma unroll
    for (int mb = 0; mb < 4; ++mb)
        #pragma unroll
        for (int nf = 0; nf < 2; ++nf) acc[mb][nf] = (f32x4){0.f, 0.f, 0.f, 0.f};

    // layer 2: 4 chunks; rolling refill crosses into o3f chunks 0,1
    #pragma unroll
    for (int i = 0; i < 4; ++i) {
        const int s = i & 1;
        half8 av[4];
        #pragma unroll
        for (int mb = 0; mb < 4; ++mb)
            av[mb] = *(const half8*)&Xs[mb * 16 + lrow][i * 32 + lk8 * 8];
        #pragma unroll
        for (int mb = 0; mb < 4; ++mb) {
            acc[mb][0] = __builtin_amdgcn_mfma_f32_16x16x32_f16(av[mb], b[s][0], acc[mb][0], 0, 0, 0);
            acc[mb][1] = __builtin_amdgcn_mfma_f32_16x16x32_f16(av[mb], b[s][1], acc[mb][1], 0, 0, 0);
        }
        if (i + 2 < 4) {
            b[s][0] = bp2[(size_t)(i + 2) * 512];
            b[s][1] = bp2[(size_t)(i + 2) * 512 + 64];
        } else {
            b[s][0] = bp3[(size_t)(i - 2) * 512];
            b[s][1] = bp3[(size_t)(i - 2) * 512 + 64];
        }
    }
    __syncthreads();

    {
        float bi0 = b2[n0 + lrow], bi1 = b2[n0 + 16 + lrow];
        #pragma unroll
        for (int mb = 0; mb < 4; ++mb)
            #pragma unroll
            for (int nf = 0; nf < 2; ++nf) {
                float bb = nf ? bi1 : bi0;
                #pragma unroll
                for (int q = 0; q < 4; ++q) {
                    float g = fmaxf(acc[mb][nf][q] + bb, 0.f);
                    Xs[mb * 16 + lk8 * 4 + q][n0 + nf * 16 + lrow] = (_Float16)g;
                }
                acc[mb][nf] = (f32x4){0.f, 0.f, 0.f, 0.f};
            }
    }
    __syncthreads();

    // layer 3: 4 chunks (slots pre-loaded with o3f chunks 0,1)
    #pragma unroll
    for (int i = 0; i < 4; ++i) {
        const int s = i & 1;
        half8 av[4];
        #pragma unroll
        for (int mb = 0; mb < 4; ++mb)
            av[mb] = *(const half8*)&Xs[mb * 16 + lrow][i * 32 + lk8 * 8];
        #pragma unroll
        for (int mb = 0; mb < 4; ++mb) {
            acc[mb][0] = __builtin_amdgcn_mfma_f32_16x16x32_f16(av[mb], b[s][0], acc[mb][0], 0, 0, 0);
            acc[mb][1] = __builtin_amdgcn_mfma_f32_16x16x32_f16(av[mb], b[s][1], acc[mb][1], 0, 0, 0);
        }
        if (i + 2 < 4) {
            b[s][0] = bp3[(size_t)(i + 2) * 512];
            b[s][1] = bp3[(size_t)(i + 2) * 512 + 64];
        }
    }

    float bi0 = b3[n0 + lrow], bi1 = b3[n0 + 16 + lrow];
    #pragma unroll
    for (int mb = 0; mb < 4; ++mb)
        #pragma unroll
        for (int q = 0; q < 4; ++q) {
            int gr = row0 + mb * 16 + lk8 * 4 + q;
            if (gr < N) {
                out[(size_t)gr * NCH + n0 + lrow]      = acc[mb][0][q] + bi0;
                out[(size_t)gr * NCH + n0 + 16 + lrow] = acc[mb][1][q] + bi1;
            }
        }
}

// ==================== fp32 fallback path (round-1, proven) ====================
__global__ __launch_bounds__(256) void k_atomwise1(
    const float* __restrict__ x, const float* __restrict__ w1,
    const float* __restrict__ b1, float* __restrict__ h,
    float* __restrict__ h2, int N)
{
    __shared__ float xs[16][NCH];
    const int row0 = blockIdx.x * 16;
    const int tid = threadIdx.x;
    #pragma unroll
    for (int t = 0; t < 8; ++t) {
        int idx = tid + t * 256;
        int r = idx >> 7, c = idx & 127;
        int gr = row0 + r;
        xs[r][c] = (gr < N) ? x[(size_t)gr * NCH + c] : 0.f;
    }
    __syncthreads();
    const int j = tid & 127;
    const int rg = tid >> 7;
    float acc[8];
    #pragma unroll
    for (int i = 0; i < 8; ++i) acc[i] = 0.f;
    for (int k = 0; k < NCH; ++k) {
        float wv = w1[(size_t)k * NCH + j];
        #pragma unroll
        for (int i = 0; i < 8; ++i)
            acc[i] = fmaf(xs[rg * 8 + i][k], wv, acc[i]);
    }
    float bv = b1[j];
    #pragma unroll
    for (int i = 0; i < 8; ++i) {
        int gr = row0 + rg * 8 + i;
        if (gr < N) {
            float v = acc[i] + bv;
            h[(size_t)gr * NCH + j]  = v;
            h2[(size_t)gr * NCH + j] = v;
        }
    }
}

__global__ __launch_bounds__(256) void k_edges_f32(
    const int* __restrict__ ei, const float* __restrict__ eattr,
    const float* __restrict__ xpos, const float* __restrict__ h,
    const float* __restrict__ mw1, const float* __restrict__ mb1,
    const float* __restrict__ mw2, const float* __restrict__ mb2,
    const float* __restrict__ mw3, const float* __restrict__ mb3,
    float* __restrict__ agg, int E)
{
    __shared__ __align__(16) float Asf[TE][292];
    __shared__ float Wsf[32][NCH];
    __shared__ int srcS[TE];
    __shared__ int dstS[TE];
    const int tid = threadIdx.x;
    const int e0 = blockIdx.x * TE;
    if (tid < TE) {
        int e = e0 + tid;
        int s = 0, d = -1;
        float r = 0.f;
        if (e < E) {
            s = ei[e]; d = ei[E + e];
            float dx = xpos[d * 3 + 0] - xpos[s * 3 + 0];
            float dy = xpos[d * 3 + 1] - xpos[s * 3 + 1];
            float dz = xpos[d * 3 + 2] - xpos[s * 3 + 2];
            r = sqrtf(dx * dx + dy * dy + dz * dz);
        }
        srcS[tid] = s; dstS[tid] = d;
        #pragma unroll
        for (int i = 0; i < 16; ++i) {
            float om = 10.f * exp2f(7.0f - 0.875f * (float)i);
            float f = r * om;
            Asf[tid][i] = sinf(f); Asf[tid][16 + i] = cosf(f);
        }
    }
    __syncthreads();
    {
        const int half = tid >> 7;
        const int c = tid & 127;
        for (int ee = 0; ee < TE; ee += 2) {
            int le = ee + half;
            int e = e0 + le;
            if (e < E) {
                Asf[le][32 + c]  = eattr[(size_t)e * NCH + c];
                Asf[le][160 + c] = h[(size_t)srcS[le] * NCH + c];
            } else { Asf[le][32 + c] = 0.f; Asf[le][160 + c] = 0.f; }
        }
    }
    const int jl = tid & 31;
    const int g  = tid >> 5;
    float acc[8][4];
    auto run_layer = [&](const float* __restrict__ Wg, int K) {
        #pragma unroll
        for (int i = 0; i < 8; ++i)
            #pragma unroll
            for (int c = 0; c < 4; ++c) acc[i][c] = 0.f;
        for (int k0 = 0; k0 < K; k0 += 32) {
            __syncthreads();
            #pragma unroll
            for (int t = 0; t < 16; ++t) {
                int idx = tid + t * 256;
                Wsf[idx >> 7][idx & 127] =
                    Wg[(size_t)(k0 + (idx >> 7)) * NCH + (idx & 127)];
            }
            __syncthreads();
            #pragma unroll
            for (int kk = 0; kk < 32; kk += 4) {
                float4 a[8];
                #pragma unroll
                for (int i = 0; i < 8; ++i)
                    a[i] = *reinterpret_cast<const float4*>(&Asf[g * 8 + i][k0 + kk]);
                #pragma unroll
                for (int u = 0; u < 4; ++u) {
                    float w0 = Wsf[kk + u][jl];
                    float w1v = Wsf[kk + u][jl + 32];
                    float w2v = Wsf[kk + u][jl + 64];
                    float w3v = Wsf[kk + u][jl + 96];
                    #pragma unroll
                    for (int i = 0; i < 8; ++i) {
                        float avv = (&a[i].x)[u];
                        acc[i][0] = fmaf(avv, w0, acc[i][0]);
                        acc[i][1] = fmaf(avv, w1v, acc[i][1]);
                        acc[i][2] = fmaf(avv, w2v, acc[i][2]);
                        acc[i][3] = fmaf(avv, w3v, acc[i][3]);
                    }
                }
            }
        }
    };
    run_layer(mw1, 288);
    #pragma unroll
    for (int i = 0; i < 8; ++i)
        #pragma unroll
        for (int c = 0; c < 4; ++c) {
            int j = jl + 32 * c;
            Asf[g * 8 + i][j] = gelu_exact(acc[i][c] + mb1[j]);
        }
    run_layer(mw2, 128);
    #pragma unroll
    for (int i = 0; i < 8; ++i)
        #pragma unroll
        for (int c = 0; c < 4; ++c) {
            int j = jl + 32 * c;
            Asf[g * 8 + i][j] = gelu_exact(acc[i][c] + mb2[j]);
        }
    run_layer(mw3, 128);
    #pragma unroll
    for (int i = 0; i < 8; ++i) {
        int d = dstS[g * 8 + i];
        if (d >= 0) {
            #pragma unroll
            for (int c = 0; c < 4; ++c) {
                int j = jl + 32 * c;
                atomicAdd(&agg[(size_t)d * NCH + j], acc[i][c] + mb3[j]);
            }
        }
    }
}

__global__ __launch_bounds__(256) void k_out(
    const float* h, const float* aggOpt,
    const float* __restrict__ w2, const float* __restrict__ b2,
    const float* __restrict__ w3, const float* __restrict__ b3,
    float* out, int N)
{
    __shared__ float hs[16][NCH];
    __shared__ float ts[16][NCH];
    const int row0 = blockIdx.x * 16;
    const int tid = threadIdx.x;
    #pragma unroll
    for (int t = 0; t < 8; ++t) {
        int idx = tid + t * 256;
        int r = idx >> 7, c = idx & 127;
        int gr = row0 + r;
        float v = 0.f;
        if (gr < N) {
            v = h[(size_t)gr * NCH + c];
            if (aggOpt) v += aggOpt[(size_t)gr * NCH + c];
        }
        hs[r][c] = v;
    }
    __syncthreads();
    const int j = tid & 127;
    const int rg = tid >> 7;
    float acc[8];
    #pragma unroll
    for (int i = 0; i < 8; ++i) acc[i] = 0.f;
    for (int k = 0; k < NCH; ++k) {
        float wv = w2[(size_t)k * NCH + j];
        #pragma unroll
        for (int i = 0; i < 8; ++i)
            acc[i] = fmaf(hs[rg * 8 + i][k], wv, acc[i]);
    }
    float bv = b2[j];
    #pragma unroll
    for (int i = 0; i < 8; ++i)
        ts[rg * 8 + i][j] = fmaxf(acc[i] + bv, 0.f);
    __syncthreads();
    float acc2[8];
    #pragma unroll
    for (int i = 0; i < 8; ++i) acc2[i] = 0.f;
    for (int k = 0; k < NCH; ++k) {
        float wv = w3[(size_t)k * NCH + j];
        #pragma unroll
        for (int i = 0; i < 8; ++i)
            acc2[i] = fmaf(ts[rg * 8 + i][k], wv, acc2[i]);
    }
    float b3v = b3[j];
    #pragma unroll
    for (int i = 0; i < 8; ++i) {
        int gr = row0 + rg * 8 + i;
        if (gr < N) out[(size_t)gr * NCH + j] = acc2[i] + b3v;
    }
}

extern "C" void kernel_launch(void* const* d_in, const int* in_sizes, int n_in,
                              void* d_out, int out_size, void* d_ws, size_t ws_size,
                              hipStream_t stream)
{
    const float* x     = (const float*)d_in[0];
    const int*   ei    = (const int*)d_in[1];
    const float* eattr = (const float*)d_in[2];
    const float* xpos  = (const float*)d_in[3];
    const float* w1    = (const float*)d_in[4];
    const float* b1    = (const float*)d_in[5];
    const float* mw1   = (const float*)d_in[6];
    const float* mb1   = (const float*)d_in[7];
    const float* mw2   = (const float*)d_in[8];
    const float* mb2   = (const float*)d_in[9];
    const float* mw3   = (const float*)d_in[10];
    const float* mb3   = (const float*)d_in[11];
    const float* w2    = (const float*)d_in[12];
    const float* b2    = (const float*)d_in[13];
    const float* w3    = (const float*)d_in[14];
    const float* b3    = (const float*)d_in[15];

    const int N = in_sizes[0] / NCH;
    const int E = in_sizes[1] / 2;

    float* h = (float*)d_out;

    const int nbscan = (N + 255) / 256;
    const int nh     = (E + 255) / 256;
    const size_t h2_bytes = (size_t)N * NCH * sizeof(_Float16);
    const size_t wchunks  = 17 + 4 + 4 + 4;   // wf | awf | o2f | o3f (frag-packed)
    const size_t wbytes   = wchunks * 4096 * sizeof(_Float16);
    const size_t csr_bytes = ((size_t)2 * N + E + nbscan) * sizeof(int);
    const bool fast = ws_size >= h2_bytes + wbytes + csr_bytes;

    if (fast) {
        _Float16* h2  = (_Float16*)d_ws;
        _Float16* wf  = (_Float16*)((char*)d_ws + h2_bytes);
        _Float16* awf = wf + 17 * 4096;
        _Float16* o2f = awf + 4 * 4096;
        _Float16* o3f = o2f + 4 * 4096;
        int* cnt  = (int*)(o3f + 4 * 4096);
        int* fill = cnt + N;
        int* perm = fill + N;
        int* bsum = perm + E;

        hipMemsetAsync(cnt, 0, (size_t)N * sizeof(int), stream);
        // fused: dst histogram + frag-pack all six weights (independent work)
        k_hist_prep<<<nh + 58, 256, 0, stream>>>(ei, cnt, E, nh,
                                                 mw1, mw2, mw3, w1, w2, w3,
                                                 wf, awf, o2f, o3f);
        if (nbscan <= 256) {
            k_scan_local<<<nbscan, 256, 0, stream>>>(cnt, fill, bsum, N);
            k_scan_bsum<<<1, 256, 0, stream>>>(bsum, nbscan);
            k_permute_off<<<(E + 255) / 256, 256, 0, stream>>>(ei, fill, bsum, perm, E);
        } else {
            k_scan_serial<<<1, 256, 0, stream>>>(cnt, fill, N);
            k_permute<<<(E + 255) / 256, 256, 0, stream>>>(ei, fill, perm, E);
        }

        const int nb = (N + 63) / 64;
        k_aw1_mfma<<<nb, 256, 0, stream>>>(x, awf, b1, h, h2, N);
        k_edges_mfma<<<(E + TF - 1) / TF, 256, 0, stream>>>(
            ei, eattr, xpos, h2, h, perm, wf, mb1, mb2, mb3, E);
        k_out_mfma<<<nb, 256, 0, stream>>>(h, o2f, b2, o3f, b3, (float*)d_out, N);
    } else {
        float* agg = (float*)d_ws;
        k_atomwise1<<<(N + 15) / 16, 256, 0, stream>>>(x, w1, b1, h, agg, N);
        hipMemsetAsync(agg, 0, (size_t)N * NCH * sizeof(float), stream);
        k_edges_f32<<<(E + TE - 1) / TE, 256, 0, stream>>>(
            ei, eattr, xpos, h, mw1, mb1, mw2, mb2, mw3, mb3, agg, E);
        k_out<<<(N + 15) / 16, 256, 0, stream>>>(h, agg, w2, b2, w3, b3,
                                                 (float*)d_out, N);
    }
}